// Round 1
// 1136.953 us; speedup vs baseline: 1.0497x; 1.0497x over previous
//
#include <hip/hip_runtime.h>
#include <hip/hip_bf16.h>
#include <math.h>

#define B_    32
#define S_    512
#define DIM_  1024
#define HID_  4096
#define E_    8
#define TOPK_ 2
#define CAP_  8
#define NSLOT_ 64

typedef __bf16 bf16_t;
typedef bf16_t bf16x8 __attribute__((ext_vector_type(8)));
typedef float  f32x4  __attribute__((ext_vector_type(4)));

__device__ __forceinline__ ushort f2bf(float f) {
    union { float f; unsigned u; } v; v.f = f;
    unsigned r = (v.u + 0x7fffu + ((v.u >> 16) & 1u)) >> 16;
    return (ushort)r;
}

// async global->LDS, 16B per lane; LDS dest is wave-uniform base + lane*16
__device__ __forceinline__ void async_cp16(const ushort* g, ushort* l) {
    __builtin_amdgcn_global_load_lds(
        (const __attribute__((address_space(1))) unsigned int*)g,
        (__attribute__((address_space(3))) unsigned int*)l, 16, 0, 0);
}

// ---------------- mean over sequence (two-stage, full-GPU) ----------------
// stage 1: grid (16, B), each block sums 32 rows -> part[b][chunk][DIM]
__global__ void k_mean_p(const float* __restrict__ rin, float* __restrict__ part) {
    int p = blockIdx.x, b = blockIdx.y;
    int d4 = threadIdx.x;                       // 256 threads x float4 = 1024 dims
    const float4* base = (const float4*)(rin + ((size_t)b * S_ + p * 32) * DIM_) + d4;
    float4 acc = {0.f, 0.f, 0.f, 0.f};
    for (int s = 0; s < 32; ++s) {
        float4 v = base[(size_t)s * (DIM_ / 4)];
        acc.x += v.x; acc.y += v.y; acc.z += v.z; acc.w += v.w;
    }
    ((float4*)(part + (size_t)(b * 16 + p) * DIM_))[d4] = acc;
}

// stage 2: grid (B), reduce 16 partials, scale by 1/S
__global__ void k_mean_f(const float* __restrict__ part, float* __restrict__ ri) {
    int b = blockIdx.x, d4 = threadIdx.x;
    float4 acc = {0.f, 0.f, 0.f, 0.f};
    for (int p = 0; p < 16; ++p) {
        float4 v = ((const float4*)(part + (size_t)(b * 16 + p) * DIM_))[d4];
        acc.x += v.x; acc.y += v.y; acc.z += v.z; acc.w += v.w;
    }
    const float inv = 1.0f / (float)S_;
    float4 o = {acc.x * inv, acc.y * inv, acc.z * inv, acc.w * inv};
    ((float4*)(ri + (size_t)b * DIM_))[d4] = o;
}

// ---------------- router ----------------
// stage 1: grid (B), one block per sample computes noisy logits [B][E]
__global__ void k_router_logits(const float* __restrict__ ri, const float* __restrict__ noise,
                                const float* __restrict__ Wg, const float* __restrict__ bg,
                                const float* __restrict__ Wn, const float* __restrict__ bn,
                                float* __restrict__ noisy) {
    __shared__ float rrow[DIM_];
    __shared__ float pg[256], pn[256];
    int b = blockIdx.x, t = threadIdx.x;
    ((float4*)rrow)[t] = ((const float4*)(ri + (size_t)b * DIM_))[t];
    __syncthreads();
    int e = t & 7, c = t >> 3;                  // 32 chunks x 8 experts
    float ag = 0.f, an = 0.f;
    for (int i = 0; i < 32; ++i) {
        float rv = rrow[c * 32 + i];
        ag += rv * Wg[(c * 32 + i) * E_ + e];
        an += rv * Wn[(c * 32 + i) * E_ + e];
    }
    pg[t] = ag; pn[t] = an;
    __syncthreads();
    for (int off = 128; off >= 8; off >>= 1) {
        if (t < off) { pg[t] += pg[t + off]; pn[t] += pn[t + off]; }
        __syncthreads();
    }
    if (t < E_) {
        float lg = pg[t] + bg[t];
        float ln = pn[t] + bn[t];
        float sp = (ln > 20.f) ? ln : log1pf(expf(ln));   // softplus
        noisy[b * E_ + t] = lg + noise[b * E_ + t] * sp;
    }
}

// stage 2: single tiny block: top-2, capacity drop, slot + per-sample tables
__global__ void k_router_assign(const float* __restrict__ noisy,
                                int* __restrict__ slot_sample, float* __restrict__ slot_gate,
                                int* __restrict__ sample_slot, float* __restrict__ sample_gate) {
    __shared__ int   top_i[B_][TOPK_];
    __shared__ float top_g[B_][TOPK_];
    int t = threadIdx.x;
    if (t < B_) {
        float v1 = -INFINITY, v2 = -INFINITY; int i1 = 0, i2 = 0;
        for (int ee = 0; ee < E_; ++ee) {
            float v = noisy[t * E_ + ee];
            if (v > v1)      { v2 = v1; i2 = i1; v1 = v; i1 = ee; }
            else if (v > v2) { v2 = v; i2 = ee; }
        }
        float g2 = expf(v2 - v1);
        float s = 1.f + g2;
        top_i[t][0] = i1; top_i[t][1] = i2;
        top_g[t][0] = 1.f / s; top_g[t][1] = g2 / s;
    }
    if (t < NSLOT_)      { slot_sample[t] = -1; slot_gate[t] = 0.f; }
    if (t < B_ * TOPK_)  { sample_slot[t] = -1; sample_gate[t] = 0.f; }
    __syncthreads();
    if (t == 0) {
        int cnt[E_];
        for (int ee = 0; ee < E_; ++ee) cnt[ee] = 0;
        for (int p = 0; p < B_ * TOPK_; ++p) {       // flat order == stable sort order
            int bb = p >> 1, kk = p & 1;
            int ee = top_i[bb][kk];
            int c = cnt[ee]++;
            if (c < CAP_) {
                int slot = ee * CAP_ + c;
                slot_sample[slot] = bb;
                slot_gate[slot]   = top_g[bb][kk];
                sample_slot[bb * TOPK_ + kk] = slot;
                sample_gate[bb * TOPK_ + kk] = top_g[bb][kk];
            }
        }
    }
}

// ---------------- conversions ----------------
__global__ void k_cvt_x(const float* __restrict__ x, ushort* __restrict__ xb, int n8) {
    int i = blockIdx.x * blockDim.x + threadIdx.x;   // 8 elements each
    if (i >= n8) return;
    const float4* p = (const float4*)x + (size_t)i * 2;
    float4 a = p[0], b = p[1];
    union { ushort s[8]; uint4 v; } u;
    u.s[0] = f2bf(a.x); u.s[1] = f2bf(a.y); u.s[2] = f2bf(a.z); u.s[3] = f2bf(a.w);
    u.s[4] = f2bf(b.x); u.s[5] = f2bf(b.y); u.s[6] = f2bf(b.z); u.s[7] = f2bf(b.w);
    ((uint4*)xb)[i] = u.v;
}

// W [K][N] fp32 -> Wt [N][K] bf16 (per expert in blockIdx.z)
__global__ void k_transpose_cvt(const float* __restrict__ W, ushort* __restrict__ Wt,
                                int K, int N) {
    __shared__ float tile[64][65];
    size_t eoff = (size_t)blockIdx.z * K * N;
    const float* Win = W + eoff;
    ushort* Wout = Wt + eoff;
    int n0 = blockIdx.x * 64, k0 = blockIdx.y * 64;
    int t = threadIdx.x;
    int r = t >> 4;             // 0..15
    int c4 = (t & 15) << 2;     // 0..60
#pragma unroll
    for (int i = 0; i < 4; ++i) {
        float4 v = *(const float4*)(Win + (size_t)(k0 + r + i * 16) * N + n0 + c4);
        tile[r + i * 16][c4 + 0] = v.x;
        tile[r + i * 16][c4 + 1] = v.y;
        tile[r + i * 16][c4 + 2] = v.z;
        tile[r + i * 16][c4 + 3] = v.w;
    }
    __syncthreads();
#pragma unroll
    for (int i = 0; i < 4; ++i) {
        int nn = r + i * 16;
        ushort4 o;
        o.x = f2bf(tile[c4 + 0][nn]);
        o.y = f2bf(tile[c4 + 1][nn]);
        o.z = f2bf(tile[c4 + 2][nn]);
        o.w = f2bf(tile[c4 + 3][nn]);
        *(ushort4*)(Wout + (size_t)(n0 + nn) * K + k0 + c4) = o;
    }
}

// ---------------- GEMM mainloop (m97 structure: 128x128 tile, BK=32, 4 waves,
// global_load_lds width=16 staging, unpadded [row][32] LDS layout) ----------------
__device__ __forceinline__ void gemm_mainloop(
    const ushort* __restrict__ Abase, int lda,
    const ushort* __restrict__ Bbase, int ldb,
    int K, ushort* lds_a, ushort* lds_b, f32x4 acc[4][4]) {
    int tid = threadIdx.x;
    int wave = tid >> 6, lane = tid & 63;
    int wm = wave & 1, wn = wave >> 1;
    int quad = lane >> 4, mr = lane & 15;
    // staging: wave w covers row-segments w and w+4 (16 rows x 32 k each = 1 KB)
    int r_lo = lane >> 2;            // 0..15 row within segment
    int kp   = (lane & 3) << 3;      // 0,8,16,24
    const ushort* a_g0 = Abase + (size_t)(wave * 16 + r_lo) * lda + kp;
    const ushort* a_g1 = Abase + (size_t)((wave + 4) * 16 + r_lo) * lda + kp;
    const ushort* b_g0 = Bbase + (size_t)(wave * 16 + r_lo) * ldb + kp;
    const ushort* b_g1 = Bbase + (size_t)((wave + 4) * 16 + r_lo) * ldb + kp;
    ushort* a_l0 = lds_a + wave * 512;           // wave-uniform LDS bases
    ushort* a_l1 = lds_a + (wave + 4) * 512;
    ushort* b_l0 = lds_b + wave * 512;
    ushort* b_l1 = lds_b + (wave + 4) * 512;
    for (int k0 = 0; k0 < K; k0 += 32) {
        __syncthreads();                          // prior iter's ds_reads done
        async_cp16(a_g0 + k0, a_l0);
        async_cp16(a_g1 + k0, a_l1);
        async_cp16(b_g0 + k0, b_l0);
        async_cp16(b_g1 + k0, b_l1);
        __syncthreads();                          // vmcnt(0) drain: tiles staged
        bf16x8 af[4], bfr[4];
#pragma unroll
        for (int i = 0; i < 4; ++i)
            af[i] = *(const bf16x8*)&lds_a[(wm * 64 + i * 16 + mr) * 32 + quad * 8];
#pragma unroll
        for (int i = 0; i < 4; ++i)
            bfr[i] = *(const bf16x8*)&lds_b[(wn * 64 + i * 16 + mr) * 32 + quad * 8];
#pragma unroll
        for (int i = 0; i < 4; ++i)
#pragma unroll
            for (int j = 0; j < 4; ++j)
                acc[i][j] = __builtin_amdgcn_mfma_f32_16x16x32_bf16(af[i], bfr[j], acc[i][j], 0, 0, 0);
    }
}

__global__ __launch_bounds__(256, 2) void k_gemm1(
    const ushort* __restrict__ xb, const ushort* __restrict__ w1t,
    const float* __restrict__ b1, const int* __restrict__ slot_sample,
    ushort* __restrict__ H) {
    __shared__ ushort As[128 * 32];
    __shared__ ushort Bs[128 * 32];
    int slot = blockIdx.z;
    int samp = slot_sample[slot];
    if (samp < 0) return;
    int e = slot >> 3;
    int mt = blockIdx.y, nt = blockIdx.x;
    const ushort* Abase = xb + ((size_t)samp * S_ + mt * 128) * DIM_;
    const ushort* Bbase = w1t + (size_t)e * HID_ * DIM_ + (size_t)(nt * 128) * DIM_;
    f32x4 acc[4][4];
#pragma unroll
    for (int i = 0; i < 4; ++i)
#pragma unroll
        for (int j = 0; j < 4; ++j) acc[i][j] = (f32x4){0.f, 0.f, 0.f, 0.f};
    gemm_mainloop(Abase, DIM_, Bbase, DIM_, DIM_, As, Bs, acc);
    int wave = threadIdx.x >> 6, lane = threadIdx.x & 63;
    int wm = wave & 1, wn = wave >> 1, quad = lane >> 4, mr = lane & 15;
    ushort* Hrow = H + ((size_t)slot * S_ + mt * 128) * HID_ + nt * 128;
#pragma unroll
    for (int j = 0; j < 4; ++j) {
        int nl = wn * 64 + j * 16 + mr;
        float bias = b1[e * HID_ + nt * 128 + nl];
#pragma unroll
        for (int i = 0; i < 4; ++i) {
#pragma unroll
            for (int r = 0; r < 4; ++r) {
                int ml = wm * 64 + i * 16 + quad * 4 + r;
                float v = acc[i][j][r] + bias;
                float g = 0.5f * v * (1.0f + erff(v * 0.70710678118654752f));
                Hrow[(size_t)ml * HID_ + nl] = f2bf(g);
            }
        }
    }
}

// per-SAMPLE gemm2: one block owns one output tile of one sample, accumulates
// over the sample's <=2 kept slots with a single acc via gate-ratio rescale:
//   acc = (g0/g1)*Y0 + Y1  -> out = g1*acc + g0*b2[e0] + g1*b2[e1]
// -> no atomics, no output memset, plain coalesced stores.
__global__ __launch_bounds__(256, 2) void k_gemm2(
    const ushort* __restrict__ H, const ushort* __restrict__ w2t,
    const float* __restrict__ b2, const int* __restrict__ sample_slot,
    const float* __restrict__ sample_gate, float* __restrict__ out) {
    __shared__ ushort As[128 * 32];
    __shared__ ushort Bs[128 * 32];
    int b = blockIdx.z;
    int sl0 = sample_slot[b * TOPK_ + 0], sl1 = sample_slot[b * TOPK_ + 1];
    float ga0 = sample_gate[b * TOPK_ + 0], ga1 = sample_gate[b * TOPK_ + 1];
    if (sl0 < 0) { sl0 = sl1; ga0 = ga1; sl1 = -1; }   // normalize: kept list front-packed
    int mt = blockIdx.y, nt = blockIdx.x;
    f32x4 acc[4][4];
#pragma unroll
    for (int i = 0; i < 4; ++i)
#pragma unroll
        for (int j = 0; j < 4; ++j) acc[i][j] = (f32x4){0.f, 0.f, 0.f, 0.f};
    if (sl0 >= 0) {
        int e0 = sl0 >> 3;
        gemm_mainloop(H + ((size_t)sl0 * S_ + mt * 128) * HID_, HID_,
                      w2t + (size_t)e0 * DIM_ * HID_ + (size_t)(nt * 128) * HID_, HID_,
                      HID_, As, Bs, acc);
    }
    if (sl1 >= 0) {
        float ratio = ga0 / ga1;
#pragma unroll
        for (int i = 0; i < 4; ++i)
#pragma unroll
            for (int j = 0; j < 4; ++j) acc[i][j] = acc[i][j] * ratio;
        int e1 = sl1 >> 3;
        gemm_mainloop(H + ((size_t)sl1 * S_ + mt * 128) * HID_, HID_,
                      w2t + (size_t)e1 * DIM_ * HID_ + (size_t)(nt * 128) * HID_, HID_,
                      HID_, As, Bs, acc);
    }
    float gfin = (sl1 >= 0) ? ga1 : ((sl0 >= 0) ? ga0 : 0.f);
    int wave = threadIdx.x >> 6, lane = threadIdx.x & 63;
    int wm = wave & 1, wn = wave >> 1, quad = lane >> 4, mr = lane & 15;
    float* Orow = out + ((size_t)b * S_ + mt * 128) * DIM_ + nt * 128;
#pragma unroll
    for (int j = 0; j < 4; ++j) {
        int nl = wn * 64 + j * 16 + mr;
        float bias = 0.f;
        if (sl0 >= 0) bias += ga0 * b2[(sl0 >> 3) * DIM_ + nt * 128 + nl];
        if (sl1 >= 0) bias += ga1 * b2[(sl1 >> 3) * DIM_ + nt * 128 + nl];
#pragma unroll
        for (int i = 0; i < 4; ++i) {
#pragma unroll
            for (int r = 0; r < 4; ++r) {
                int ml = wm * 64 + i * 16 + quad * 4 + r;
                Orow[(size_t)ml * DIM_ + nl] = acc[i][j][r] * gfin + bias;
            }
        }
    }
}

// ---------------- launch ----------------
extern "C" void kernel_launch(void* const* d_in, const int* in_sizes, int n_in,
                              void* d_out, int out_size, void* d_ws, size_t ws_size,
                              hipStream_t stream) {
    const float* rin   = (const float*)d_in[0];
    const float* x     = (const float*)d_in[1];
    const float* noise = (const float*)d_in[2];
    const float* Wg    = (const float*)d_in[3];
    const float* bg    = (const float*)d_in[4];
    const float* Wn    = (const float*)d_in[5];
    const float* bn    = (const float*)d_in[6];
    const float* W1    = (const float*)d_in[7];
    const float* b1    = (const float*)d_in[8];
    const float* W2    = (const float*)d_in[9];
    const float* b2    = (const float*)d_in[10];
    float* out = (float*)d_out;

    char* ws = (char*)d_ws;
    float*  ri          = (float*)ws;                         // 131072 B
    int*    slot_sample = (int*)(ws + 131072);                // 256 B
    float*  slot_gate   = (float*)(ws + 131328);              // 256 B
    int*    sample_slot = (int*)(ws + 131584);                // 256 B
    float*  sample_gate = (float*)(ws + 131840);              // 256 B   (header ends < 135168)
    ushort* xb  = (ushort*)(ws + 135168);                     // 32 MB
    ushort* w1t = (ushort*)(ws + 135168 + 33554432);          // 64 MB
    ushort* w2t = (ushort*)(ws + 135168 + 33554432 + 67108864);     // 64 MB
    ushort* H   = (ushort*)(ws + 135168 + 33554432 + 2 * 67108864); // 256 MB
    // scratch for mean/router lives in the H region (H is written only later by gemm1)
    float* part  = (float*)H;                                 // 2 MB  (32*16*1024 f32)
    float* noisy = (float*)((char*)H + 2097152);              // 1 KB

    k_mean_p<<<dim3(16, B_), 256, 0, stream>>>(rin, part);
    k_mean_f<<<B_, 256, 0, stream>>>(part, ri);
    k_router_logits<<<B_, 256, 0, stream>>>(ri, noise, Wg, bg, Wn, bn, noisy);
    k_router_assign<<<1, 256, 0, stream>>>(noisy, slot_sample, slot_gate,
                                           sample_slot, sample_gate);
    k_cvt_x<<<(B_ * S_ * DIM_ / 8 + 255) / 256, 256, 0, stream>>>(x, xb, B_ * S_ * DIM_ / 8);
    k_transpose_cvt<<<dim3(HID_ / 64, DIM_ / 64, E_), 256, 0, stream>>>(W1, w1t, DIM_, HID_);
    k_transpose_cvt<<<dim3(DIM_ / 64, HID_ / 64, E_), 256, 0, stream>>>(W2, w2t, HID_, DIM_);
    k_gemm1<<<dim3(HID_ / 128, S_ / 128, NSLOT_), 256, 0, stream>>>(xb, w1t, b1, slot_sample, H);
    k_gemm2<<<dim3(DIM_ / 128, S_ / 128, B_), 256, 0, stream>>>(H, w2t, b2, sample_slot,
                                                                sample_gate, out);
}

// Round 3
// 1067.496 us; speedup vs baseline: 1.1180x; 1.0651x over previous
//
#include <hip/hip_runtime.h>
#include <hip/hip_bf16.h>
#include <math.h>

#define B_    32
#define S_    512
#define DIM_  1024
#define HID_  4096
#define E_    8
#define TOPK_ 2
#define CAP_  8
#define NSLOT_ 64

typedef __bf16 bf16_t;
typedef bf16_t bf16x8 __attribute__((ext_vector_type(8)));
typedef float  f32x4  __attribute__((ext_vector_type(4)));

__device__ __forceinline__ ushort f2bf(float f) {
    union { float f; unsigned u; } v; v.f = f;
    unsigned r = (v.u + 0x7fffu + ((v.u >> 16) & 1u)) >> 16;
    return (ushort)r;
}

// async global->LDS, 16B per lane; LDS dest is wave-uniform base + lane*16
__device__ __forceinline__ void async_cp16(const ushort* g, ushort* l) {
    __builtin_amdgcn_global_load_lds(
        (const __attribute__((address_space(1))) unsigned int*)g,
        (__attribute__((address_space(3))) unsigned int*)l, 16, 0, 0);
}

// ---------------- mean over sequence (two-stage, full-GPU) ----------------
__global__ void k_mean_p(const float* __restrict__ rin, float* __restrict__ part) {
    int p = blockIdx.x, b = blockIdx.y;
    int d4 = threadIdx.x;
    const float4* base = (const float4*)(rin + ((size_t)b * S_ + p * 32) * DIM_) + d4;
    float4 acc = {0.f, 0.f, 0.f, 0.f};
    for (int s = 0; s < 32; ++s) {
        float4 v = base[(size_t)s * (DIM_ / 4)];
        acc.x += v.x; acc.y += v.y; acc.z += v.z; acc.w += v.w;
    }
    ((float4*)(part + (size_t)(b * 16 + p) * DIM_))[d4] = acc;
}

__global__ void k_mean_f(const float* __restrict__ part, float* __restrict__ ri) {
    int b = blockIdx.x, d4 = threadIdx.x;
    float4 acc = {0.f, 0.f, 0.f, 0.f};
    for (int p = 0; p < 16; ++p) {
        float4 v = ((const float4*)(part + (size_t)(b * 16 + p) * DIM_))[d4];
        acc.x += v.x; acc.y += v.y; acc.z += v.z; acc.w += v.w;
    }
    const float inv = 1.0f / (float)S_;
    float4 o = {acc.x * inv, acc.y * inv, acc.z * inv, acc.w * inv};
    ((float4*)(ri + (size_t)b * DIM_))[d4] = o;
}

// ---------------- router ----------------
__global__ void k_router_logits(const float* __restrict__ ri, const float* __restrict__ noise,
                                const float* __restrict__ Wg, const float* __restrict__ bg,
                                const float* __restrict__ Wn, const float* __restrict__ bn,
                                float* __restrict__ noisy) {
    __shared__ float rrow[DIM_];
    __shared__ float pg[256], pn[256];
    int b = blockIdx.x, t = threadIdx.x;
    ((float4*)rrow)[t] = ((const float4*)(ri + (size_t)b * DIM_))[t];
    __syncthreads();
    int e = t & 7, c = t >> 3;
    float ag = 0.f, an = 0.f;
    for (int i = 0; i < 32; ++i) {
        float rv = rrow[c * 32 + i];
        ag += rv * Wg[(c * 32 + i) * E_ + e];
        an += rv * Wn[(c * 32 + i) * E_ + e];
    }
    pg[t] = ag; pn[t] = an;
    __syncthreads();
    for (int off = 128; off >= 8; off >>= 1) {
        if (t < off) { pg[t] += pg[t + off]; pn[t] += pn[t + off]; }
        __syncthreads();
    }
    if (t < E_) {
        float lg = pg[t] + bg[t];
        float ln = pn[t] + bn[t];
        float sp = (ln > 20.f) ? ln : log1pf(expf(ln));
        noisy[b * E_ + t] = lg + noise[b * E_ + t] * sp;
    }
}

__global__ void k_router_assign(const float* __restrict__ noisy,
                                int* __restrict__ slot_sample, float* __restrict__ slot_gate,
                                int* __restrict__ sample_slot, float* __restrict__ sample_gate) {
    __shared__ int   top_i[B_][TOPK_];
    __shared__ float top_g[B_][TOPK_];
    int t = threadIdx.x;
    if (t < B_) {
        float v1 = -INFINITY, v2 = -INFINITY; int i1 = 0, i2 = 0;
        for (int ee = 0; ee < E_; ++ee) {
            float v = noisy[t * E_ + ee];
            if (v > v1)      { v2 = v1; i2 = i1; v1 = v; i1 = ee; }
            else if (v > v2) { v2 = v; i2 = ee; }
        }
        float g2 = expf(v2 - v1);
        float s = 1.f + g2;
        top_i[t][0] = i1; top_i[t][1] = i2;
        top_g[t][0] = 1.f / s; top_g[t][1] = g2 / s;
    }
    if (t < NSLOT_)      { slot_sample[t] = -1; slot_gate[t] = 0.f; }
    if (t < B_ * TOPK_)  { sample_slot[t] = -1; sample_gate[t] = 0.f; }
    __syncthreads();
    if (t == 0) {
        int cnt[E_];
        for (int ee = 0; ee < E_; ++ee) cnt[ee] = 0;
        for (int p = 0; p < B_ * TOPK_; ++p) {
            int bb = p >> 1, kk = p & 1;
            int ee = top_i[bb][kk];
            int c = cnt[ee]++;
            if (c < CAP_) {
                int slot = ee * CAP_ + c;
                slot_sample[slot] = bb;
                slot_gate[slot]   = top_g[bb][kk];
                sample_slot[bb * TOPK_ + kk] = slot;
                sample_gate[bb * TOPK_ + kk] = top_g[bb][kk];
            }
        }
    }
}

// ---------------- conversions ----------------
__global__ void k_cvt_x(const float* __restrict__ x, ushort* __restrict__ xb, int n8) {
    int i = blockIdx.x * blockDim.x + threadIdx.x;
    if (i >= n8) return;
    const float4* p = (const float4*)x + (size_t)i * 2;
    float4 a = p[0], b = p[1];
    union { ushort s[8]; uint4 v; } u;
    u.s[0] = f2bf(a.x); u.s[1] = f2bf(a.y); u.s[2] = f2bf(a.z); u.s[3] = f2bf(a.w);
    u.s[4] = f2bf(b.x); u.s[5] = f2bf(b.y); u.s[6] = f2bf(b.z); u.s[7] = f2bf(b.w);
    ((uint4*)xb)[i] = u.v;
}

__global__ void k_transpose_cvt(const float* __restrict__ W, ushort* __restrict__ Wt,
                                int K, int N) {
    __shared__ float tile[64][65];
    size_t eoff = (size_t)blockIdx.z * K * N;
    const float* Win = W + eoff;
    ushort* Wout = Wt + eoff;
    int n0 = blockIdx.x * 64, k0 = blockIdx.y * 64;
    int t = threadIdx.x;
    int r = t >> 4;
    int c4 = (t & 15) << 2;
#pragma unroll
    for (int i = 0; i < 4; ++i) {
        float4 v = *(const float4*)(Win + (size_t)(k0 + r + i * 16) * N + n0 + c4);
        tile[r + i * 16][c4 + 0] = v.x;
        tile[r + i * 16][c4 + 1] = v.y;
        tile[r + i * 16][c4 + 2] = v.z;
        tile[r + i * 16][c4 + 3] = v.w;
    }
    __syncthreads();
#pragma unroll
    for (int i = 0; i < 4; ++i) {
        int nn = r + i * 16;
        ushort4 o;
        o.x = f2bf(tile[c4 + 0][nn]);
        o.y = f2bf(tile[c4 + 1][nn]);
        o.z = f2bf(tile[c4 + 2][nn]);
        o.w = f2bf(tile[c4 + 3][nn]);
        *(ushort4*)(Wout + (size_t)(n0 + nn) * K + k0 + c4) = o;
    }
}

// ---------------- deep-pipelined 256x256 GEMM mainloop ----------------
// 512 threads = 8 waves (2M x 4N), per-wave C = 128x64 (8x4 frags of 16x16).
// BK=32, 4 LDS slots (A 16KB + B 16KB each) = 128 KiB, prefetch distance 2,
// counted vmcnt(4) at tile boundaries (never 0 mid-loop), T2 XOR bank-swizzle
// on ds_read with inverse-swizzled global staging source (linear gload_lds dest),
// raw s_barrier + lgkmcnt(0)+sched_barrier(0), setprio(1) around MFMA clusters.
__device__ __forceinline__ void gemm_mainloop256(
    const ushort* __restrict__ Abase, int lda,
    const ushort* __restrict__ Bbase, int ldb,
    int K, ushort* lds, f32x4 acc[8][4]) {
    const int tid  = threadIdx.x;
    const int wave = tid >> 6, lane = tid & 63;
    const int wm = wave >> 2, wn = wave & 3;
    const int quad = lane >> 4, mr = lane & 15;
    const int nt = K >> 5;
    // swizzle: byte ^= ((row&3)<<4) ^ (((row>>2)&1)<<6)
    const unsigned swz = (((unsigned)(mr & 3)) << 4) | (((unsigned)((mr >> 2) & 1)) << 6);
    unsigned offA[8], offB[4];
#pragma unroll
    for (int i = 0; i < 8; ++i)
        offA[i] = (((unsigned)(wm * 128 + i * 16 + mr) * 64u + (unsigned)quad * 16u) ^ swz);
#pragma unroll
    for (int j = 0; j < 4; ++j)
        offB[j] = 16384u + (((unsigned)(wn * 64 + j * 16 + mr) * 64u + (unsigned)quad * 16u) ^ swz);
    // staging: wave stages segments 2w, 2w+1 (1 KiB each) per region; linear LDS
    // dest, inverse-swizzled global source (rule: both-sides-or-neither).
    int srow[2], squad[2];
    unsigned sldso[2];
#pragma unroll
    for (int h = 0; h < 2; ++h) {
        unsigned tt = (unsigned)(2 * wave + h) * 1024u + (unsigned)lane * 16u;
        int row = (int)(((tt >> 7) << 1) | (((tt >> 6) & 1u) ^ ((tt >> 8) & 1u)));
        int q   = (int)(((tt >> 4) & 3u) ^ (unsigned)(row & 3));
        srow[h] = row; squad[h] = q;
        sldso[h] = (unsigned)(2 * wave + h) * 1024u;
    }
    const ushort* gA0 = Abase + (size_t)srow[0] * lda + squad[0] * 8;
    const ushort* gA1 = Abase + (size_t)srow[1] * lda + squad[1] * 8;
    const ushort* gB0 = Bbase + (size_t)srow[0] * ldb + squad[0] * 8;
    const ushort* gB1 = Bbase + (size_t)srow[1] * ldb + squad[1] * 8;
    char* ldsb = (char*)lds;
#define STAGE_A_(tt_) do { \
        char* s_ = ldsb + ((tt_) & 3) * 32768; int k0_ = (tt_) * 32; \
        async_cp16(gA0 + k0_, (ushort*)(s_ + sldso[0])); \
        async_cp16(gA1 + k0_, (ushort*)(s_ + sldso[1])); } while (0)
#define STAGE_B_(tt_) do { \
        char* s_ = ldsb + ((tt_) & 3) * 32768 + 16384; int k0_ = (tt_) * 32; \
        async_cp16(gB0 + k0_, (ushort*)(s_ + sldso[0])); \
        async_cp16(gB1 + k0_, (ushort*)(s_ + sldso[1])); } while (0)
    // prologue: tiles 0,1 staged; wait tile0 (vmcnt(4): 4 of 8 loads may remain)
    STAGE_A_(0); STAGE_B_(0); STAGE_A_(1); STAGE_B_(1);
    asm volatile("s_waitcnt vmcnt(4)" ::: "memory");
    __builtin_amdgcn_s_barrier();
    for (int t = 0; t < nt; ++t) {
        const char* sb = ldsb + (t & 3) * 32768;
        bf16x8 a[4], b[4];
        // ---- phase 0: read A[mq=0] + all B; stage A of t+2 ----
#pragma unroll
        for (int i = 0; i < 4; ++i) a[i] = *(const bf16x8*)(sb + offA[i]);
#pragma unroll
        for (int j = 0; j < 4; ++j) b[j] = *(const bf16x8*)(sb + offB[j]);
        if (t + 2 < nt) STAGE_A_(t + 2);
        __builtin_amdgcn_s_barrier();
        asm volatile("s_waitcnt lgkmcnt(0)" ::: "memory");
        __builtin_amdgcn_sched_barrier(0);
        __builtin_amdgcn_s_setprio(1);
#pragma unroll
        for (int i = 0; i < 4; ++i)
#pragma unroll
            for (int j = 0; j < 4; ++j)
                acc[i][j] = __builtin_amdgcn_mfma_f32_16x16x32_bf16(a[i], b[j], acc[i][j], 0, 0, 0);
        __builtin_amdgcn_s_setprio(0);
        __builtin_amdgcn_s_barrier();
        // ---- phase 1: read A[mq=1]; stage B of t+2 ----
#pragma unroll
        for (int i = 0; i < 4; ++i) a[i] = *(const bf16x8*)(sb + offA[4 + i]);
        if (t + 2 < nt) STAGE_B_(t + 2);
        __builtin_amdgcn_s_barrier();
        asm volatile("s_waitcnt lgkmcnt(0)" ::: "memory");
        __builtin_amdgcn_sched_barrier(0);
        __builtin_amdgcn_s_setprio(1);
#pragma unroll
        for (int i = 0; i < 4; ++i)
#pragma unroll
            for (int j = 0; j < 4; ++j)
                acc[4 + i][j] = __builtin_amdgcn_mfma_f32_16x16x32_bf16(a[i], b[j], acc[4 + i][j], 0, 0, 0);
        __builtin_amdgcn_s_setprio(0);
        // tile boundary: complete tile t+1's 4 loads; keep t+2's 4 in flight
        if (t + 2 < nt)      { asm volatile("s_waitcnt vmcnt(4)" ::: "memory"); }
        else if (t + 1 < nt) { asm volatile("s_waitcnt vmcnt(0)" ::: "memory"); }
        __builtin_amdgcn_s_barrier();
    }
#undef STAGE_A_
#undef STAGE_B_
}

// gemm1: per-slot, XCD-grouped 1D grid so the 16 nt-siblings sharing an A panel
// land on one XCD's L2. F = (u%8) + 8*(nt + 16*(u/8)), u = slot*2 + mt.
__global__ __launch_bounds__(512, 2) void k_gemm1(
    const ushort* __restrict__ xb, const ushort* __restrict__ w1t,
    const float* __restrict__ b1, const int* __restrict__ slot_sample,
    ushort* __restrict__ H) {
    __shared__ __attribute__((aligned(16))) ushort lds[65536];   // 128 KiB
    unsigned F = blockIdx.x;
    int low3 = F & 7; unsigned rest = F >> 3;
    int nt_ = rest & 15; int g = rest >> 4;
    int u1 = g * 8 + low3;                 // 0..127
    int slot = u1 >> 1, mt = u1 & 1;
    int samp = slot_sample[slot];
    if (samp < 0) return;
    int e = slot >> 3;
    const ushort* Abase = xb + ((size_t)samp * S_ + mt * 256) * DIM_;
    const ushort* Bbase = w1t + (size_t)e * HID_ * DIM_ + (size_t)(nt_ * 256) * DIM_;
    f32x4 acc[8][4];
#pragma unroll
    for (int i = 0; i < 8; ++i)
#pragma unroll
        for (int j = 0; j < 4; ++j) acc[i][j] = (f32x4){0.f, 0.f, 0.f, 0.f};
    gemm_mainloop256(Abase, DIM_, Bbase, DIM_, DIM_, lds, acc);
    int wave = threadIdx.x >> 6, lane = threadIdx.x & 63;
    int wm = wave >> 2, wn = wave & 3, quad = lane >> 4, mr = lane & 15;
    ushort* Hrow = H + ((size_t)slot * S_ + mt * 256) * HID_ + nt_ * 256;
#pragma unroll
    for (int j = 0; j < 4; ++j) {
        int nl = wn * 64 + j * 16 + mr;
        float bias = b1[e * HID_ + nt_ * 256 + nl];
#pragma unroll
        for (int i = 0; i < 8; ++i) {
#pragma unroll
            for (int r = 0; r < 4; ++r) {
                int ml = wm * 128 + i * 16 + quad * 4 + r;
                float v = acc[i][j][r] + bias;
                float gl = 0.5f * v * (1.0f + erff(v * 0.70710678118654752f));
                Hrow[(size_t)ml * HID_ + nl] = f2bf(gl);
            }
        }
    }
}

// gemm2: per-sample (no atomics), XCD-grouped so the 4 nt-siblings sharing an
// H slab land on one XCD's L2. F = (u%8) + 8*(nt + 4*(u/8)), u = b*2 + mt.
__global__ __launch_bounds__(512, 2) void k_gemm2(
    const ushort* __restrict__ H, const ushort* __restrict__ w2t,
    const float* __restrict__ b2, const int* __restrict__ sample_slot,
    const float* __restrict__ sample_gate, float* __restrict__ out) {
    __shared__ __attribute__((aligned(16))) ushort lds[65536];   // 128 KiB
    unsigned F = blockIdx.x;
    int low3 = F & 7; unsigned rest = F >> 3;
    int nt_ = rest & 3; int g = rest >> 2;
    int u = g * 8 + low3;                  // 0..63
    int b = u >> 1, mt = u & 1;
    int sl0 = sample_slot[b * TOPK_ + 0], sl1 = sample_slot[b * TOPK_ + 1];
    float ga0 = sample_gate[b * TOPK_ + 0], ga1 = sample_gate[b * TOPK_ + 1];
    if (sl0 < 0) { sl0 = sl1; ga0 = ga1; sl1 = -1; }
    f32x4 acc[8][4];
#pragma unroll
    for (int i = 0; i < 8; ++i)
#pragma unroll
        for (int j = 0; j < 4; ++j) acc[i][j] = (f32x4){0.f, 0.f, 0.f, 0.f};
    if (sl0 >= 0) {
        int e0 = sl0 >> 3;
        gemm_mainloop256(H + ((size_t)sl0 * S_ + mt * 256) * HID_, HID_,
                         w2t + (size_t)e0 * DIM_ * HID_ + (size_t)(nt_ * 256) * HID_, HID_,
                         HID_, lds, acc);
    }
    if (sl1 >= 0) {
        float ratio = ga0 / ga1;
#pragma unroll
        for (int i = 0; i < 8; ++i)
#pragma unroll
            for (int j = 0; j < 4; ++j) acc[i][j] = acc[i][j] * ratio;
        int e1 = sl1 >> 3;
        gemm_mainloop256(H + ((size_t)sl1 * S_ + mt * 256) * HID_, HID_,
                         w2t + (size_t)e1 * DIM_ * HID_ + (size_t)(nt_ * 256) * HID_, HID_,
                         HID_, lds, acc);
    }
    float gfin = (sl1 >= 0) ? ga1 : ((sl0 >= 0) ? ga0 : 0.f);
    int wave = threadIdx.x >> 6, lane = threadIdx.x & 63;
    int wm = wave >> 2, wn = wave & 3, quad = lane >> 4, mr = lane & 15;
    float* Orow = out + ((size_t)b * S_ + mt * 256) * DIM_ + nt_ * 256;
#pragma unroll
    for (int j = 0; j < 4; ++j) {
        int nl = wn * 64 + j * 16 + mr;
        float bias = 0.f;
        if (sl0 >= 0) bias += ga0 * b2[(sl0 >> 3) * DIM_ + nt_ * 256 + nl];
        if (sl1 >= 0) bias += ga1 * b2[(sl1 >> 3) * DIM_ + nt_ * 256 + nl];
#pragma unroll
        for (int i = 0; i < 8; ++i) {
#pragma unroll
            for (int r = 0; r < 4; ++r) {
                int ml = wm * 128 + i * 16 + quad * 4 + r;
                Orow[(size_t)ml * DIM_ + nl] = acc[i][j][r] * gfin + bias;
            }
        }
    }
}

// ---------------- launch ----------------
extern "C" void kernel_launch(void* const* d_in, const int* in_sizes, int n_in,
                              void* d_out, int out_size, void* d_ws, size_t ws_size,
                              hipStream_t stream) {
    const float* rin   = (const float*)d_in[0];
    const float* x     = (const float*)d_in[1];
    const float* noise = (const float*)d_in[2];
    const float* Wg    = (const float*)d_in[3];
    const float* bg    = (const float*)d_in[4];
    const float* Wn    = (const float*)d_in[5];
    const float* bn    = (const float*)d_in[6];
    const float* W1    = (const float*)d_in[7];
    const float* b1    = (const float*)d_in[8];
    const float* W2    = (const float*)d_in[9];
    const float* b2    = (const float*)d_in[10];
    float* out = (float*)d_out;

    char* ws = (char*)d_ws;
    float*  ri          = (float*)ws;
    int*    slot_sample = (int*)(ws + 131072);
    float*  slot_gate   = (float*)(ws + 131328);
    int*    sample_slot = (int*)(ws + 131584);
    float*  sample_gate = (float*)(ws + 131840);
    ushort* xb  = (ushort*)(ws + 135168);                           // 32 MB
    ushort* w1t = (ushort*)(ws + 135168 + 33554432);                // 64 MB
    ushort* w2t = (ushort*)(ws + 135168 + 33554432 + 67108864);     // 64 MB
    ushort* H   = (ushort*)(ws + 135168 + 33554432 + 2 * 67108864); // 256 MB
    float* part  = (float*)H;                                       // scratch (pre-gemm1)
    float* noisy = (float*)((char*)H + 2097152);

    k_mean_p<<<dim3(16, B_), 256, 0, stream>>>(rin, part);
    k_mean_f<<<B_, 256, 0, stream>>>(part, ri);
    k_router_logits<<<B_, 256, 0, stream>>>(ri, noise, Wg, bg, Wn, bn, noisy);
    k_router_assign<<<1, 256, 0, stream>>>(noisy, slot_sample, slot_gate,
                                           sample_slot, sample_gate);
    k_cvt_x<<<(B_ * S_ * DIM_ / 8 + 255) / 256, 256, 0, stream>>>(x, xb, B_ * S_ * DIM_ / 8);
    k_transpose_cvt<<<dim3(HID_ / 64, DIM_ / 64, E_), 256, 0, stream>>>(W1, w1t, DIM_, HID_);
    k_transpose_cvt<<<dim3(DIM_ / 64, HID_ / 64, E_), 256, 0, stream>>>(W2, w2t, HID_, DIM_);
    k_gemm1<<<128 * 16, 512, 0, stream>>>(xb, w1t, b1, slot_sample, H);
    k_gemm2<<<64 * 4, 512, 0, stream>>>(H, w2t, b2, sample_slot, sample_gate, out);
}

// Round 4
// 992.940 us; speedup vs baseline: 1.2020x; 1.0751x over previous
//
#include <hip/hip_runtime.h>
#include <hip/hip_bf16.h>
#include <math.h>

#define B_    32
#define S_    512
#define DIM_  1024
#define HID_  4096
#define E_    8
#define TOPK_ 2
#define CAP_  8
#define NSLOT_ 64

typedef __bf16 bf16_t;
typedef bf16_t bf16x8 __attribute__((ext_vector_type(8)));
typedef float  f32x4  __attribute__((ext_vector_type(4)));

__device__ __forceinline__ ushort f2bf(float f) {
    union { float f; unsigned u; } v; v.f = f;
    unsigned r = (v.u + 0x7fffu + ((v.u >> 16) & 1u)) >> 16;
    return (ushort)r;
}

// async global->LDS, 16B per lane; LDS dest is wave-uniform base + lane*16
__device__ __forceinline__ void async_cp16(const ushort* g, ushort* l) {
    __builtin_amdgcn_global_load_lds(
        (const __attribute__((address_space(1))) unsigned int*)g,
        (__attribute__((address_space(3))) unsigned int*)l, 16, 0, 0);
}

// ---------------- mean over sequence (two-stage, full-GPU) ----------------
__global__ void k_mean_p(const float* __restrict__ rin, float* __restrict__ part) {
    int p = blockIdx.x, b = blockIdx.y;
    int d4 = threadIdx.x;
    const float4* base = (const float4*)(rin + ((size_t)b * S_ + p * 32) * DIM_) + d4;
    float4 acc = {0.f, 0.f, 0.f, 0.f};
    for (int s = 0; s < 32; ++s) {
        float4 v = base[(size_t)s * (DIM_ / 4)];
        acc.x += v.x; acc.y += v.y; acc.z += v.z; acc.w += v.w;
    }
    ((float4*)(part + (size_t)(b * 16 + p) * DIM_))[d4] = acc;
}

__global__ void k_mean_f(const float* __restrict__ part, float* __restrict__ ri) {
    int b = blockIdx.x, d4 = threadIdx.x;
    float4 acc = {0.f, 0.f, 0.f, 0.f};
    for (int p = 0; p < 16; ++p) {
        float4 v = ((const float4*)(part + (size_t)(b * 16 + p) * DIM_))[d4];
        acc.x += v.x; acc.y += v.y; acc.z += v.z; acc.w += v.w;
    }
    const float inv = 1.0f / (float)S_;
    float4 o = {acc.x * inv, acc.y * inv, acc.z * inv, acc.w * inv};
    ((float4*)(ri + (size_t)b * DIM_))[d4] = o;
}

// ---------------- router ----------------
__global__ void k_router_logits(const float* __restrict__ ri, const float* __restrict__ noise,
                                const float* __restrict__ Wg, const float* __restrict__ bg,
                                const float* __restrict__ Wn, const float* __restrict__ bn,
                                float* __restrict__ noisy) {
    __shared__ float rrow[DIM_];
    __shared__ float pg[256], pn[256];
    int b = blockIdx.x, t = threadIdx.x;
    ((float4*)rrow)[t] = ((const float4*)(ri + (size_t)b * DIM_))[t];
    __syncthreads();
    int e = t & 7, c = t >> 3;
    float ag = 0.f, an = 0.f;
    for (int i = 0; i < 32; ++i) {
        float rv = rrow[c * 32 + i];
        ag += rv * Wg[(c * 32 + i) * E_ + e];
        an += rv * Wn[(c * 32 + i) * E_ + e];
    }
    pg[t] = ag; pn[t] = an;
    __syncthreads();
    for (int off = 128; off >= 8; off >>= 1) {
        if (t < off) { pg[t] += pg[t + off]; pn[t] += pn[t + off]; }
        __syncthreads();
    }
    if (t < E_) {
        float lg = pg[t] + bg[t];
        float ln = pn[t] + bn[t];
        float sp = (ln > 20.f) ? ln : log1pf(expf(ln));
        noisy[b * E_ + t] = lg + noise[b * E_ + t] * sp;
    }
}

__global__ void k_router_assign(const float* __restrict__ noisy,
                                int* __restrict__ slot_sample, float* __restrict__ slot_gate,
                                int* __restrict__ sample_slot, float* __restrict__ sample_gate) {
    __shared__ int   top_i[B_][TOPK_];
    __shared__ float top_g[B_][TOPK_];
    int t = threadIdx.x;
    if (t < B_) {
        float v1 = -INFINITY, v2 = -INFINITY; int i1 = 0, i2 = 0;
        for (int ee = 0; ee < E_; ++ee) {
            float v = noisy[t * E_ + ee];
            if (v > v1)      { v2 = v1; i2 = i1; v1 = v; i1 = ee; }
            else if (v > v2) { v2 = v; i2 = ee; }
        }
        float g2 = expf(v2 - v1);
        float s = 1.f + g2;
        top_i[t][0] = i1; top_i[t][1] = i2;
        top_g[t][0] = 1.f / s; top_g[t][1] = g2 / s;
    }
    if (t < NSLOT_)      { slot_sample[t] = -1; slot_gate[t] = 0.f; }
    if (t < B_ * TOPK_)  { sample_slot[t] = -1; sample_gate[t] = 0.f; }
    __syncthreads();
    if (t == 0) {
        int cnt[E_];
        for (int ee = 0; ee < E_; ++ee) cnt[ee] = 0;
        for (int p = 0; p < B_ * TOPK_; ++p) {
            int bb = p >> 1, kk = p & 1;
            int ee = top_i[bb][kk];
            int c = cnt[ee]++;
            if (c < CAP_) {
                int slot = ee * CAP_ + c;
                slot_sample[slot] = bb;
                slot_gate[slot]   = top_g[bb][kk];
                sample_slot[bb * TOPK_ + kk] = slot;
                sample_gate[bb * TOPK_ + kk] = top_g[bb][kk];
            }
        }
    }
}

// ---------------- conversions ----------------
__global__ void k_cvt_x(const float* __restrict__ x, ushort* __restrict__ xb, int n8) {
    int i = blockIdx.x * blockDim.x + threadIdx.x;
    if (i >= n8) return;
    const float4* p = (const float4*)x + (size_t)i * 2;
    float4 a = p[0], b = p[1];
    union { ushort s[8]; uint4 v; } u;
    u.s[0] = f2bf(a.x); u.s[1] = f2bf(a.y); u.s[2] = f2bf(a.z); u.s[3] = f2bf(a.w);
    u.s[4] = f2bf(b.x); u.s[5] = f2bf(b.y); u.s[6] = f2bf(b.z); u.s[7] = f2bf(b.w);
    ((uint4*)xb)[i] = u.v;
}

__global__ void k_transpose_cvt(const float* __restrict__ W, ushort* __restrict__ Wt,
                                int K, int N) {
    __shared__ float tile[64][65];
    size_t eoff = (size_t)blockIdx.z * K * N;
    const float* Win = W + eoff;
    ushort* Wout = Wt + eoff;
    int n0 = blockIdx.x * 64, k0 = blockIdx.y * 64;
    int t = threadIdx.x;
    int r = t >> 4;
    int c4 = (t & 15) << 2;
#pragma unroll
    for (int i = 0; i < 4; ++i) {
        float4 v = *(const float4*)(Win + (size_t)(k0 + r + i * 16) * N + n0 + c4);
        tile[r + i * 16][c4 + 0] = v.x;
        tile[r + i * 16][c4 + 1] = v.y;
        tile[r + i * 16][c4 + 2] = v.z;
        tile[r + i * 16][c4 + 3] = v.w;
    }
    __syncthreads();
#pragma unroll
    for (int i = 0; i < 4; ++i) {
        int nn = r + i * 16;
        ushort4 o;
        o.x = f2bf(tile[c4 + 0][nn]);
        o.y = f2bf(tile[c4 + 1][nn]);
        o.z = f2bf(tile[c4 + 2][nn]);
        o.w = f2bf(tile[c4 + 3][nn]);
        *(ushort4*)(Wout + (size_t)(n0 + nn) * K + k0 + c4) = o;
    }
}

// ---------------- 256x256 GEMM mainloop, BK=64, 4 phases/K-tile ----------------
// 512 threads = 8 waves (2M x 4N), per-wave C = 128x64 (8x4 frags of 16x16).
// LDS: A = 2 slots x 32KB, B = 2 slots x 32KB (128 KiB). One barrier per phase.
// B-frags loaded once per K-tile (held in regs). Stage units issued in
// consumption order {Bh0,Bh1,Au0..Au3} with staggered counted vmcnt(4/5/6/3):
// every unit has >=3 phases (~1 K-tile) of latency cover; never drains to 0
// mid-loop. st_16x32-style swizzle: byte ^= ((row&7)<<4) on ds_read; DMA dest
// linear, global source inverse-permuted (both-sides rule).
__device__ __forceinline__ void gemm_mainloop256(
    const ushort* __restrict__ Abase, int lda,
    const ushort* __restrict__ Bbase, int ldb,
    int K, ushort* lds, f32x4 acc[8][4]) {
    const int tid  = threadIdx.x;
    const int wave = tid >> 6, lane = tid & 63;
    const int wm = wave >> 2, wn = wave & 3;
    const int quad = lane >> 4, mr = lane & 15;
    const int nt = K >> 6;
    char* const ldsc = (char*)lds;
    const int swzv = (mr & 7) << 4;
    const int kp0 = (quad * 16) ^ swzv;          // ks=0 byte offset within 128B row
    const int kp1 = (64 + quad * 16) ^ swzv;     // ks=1
    // staging lane geometry: lane covers row rowoff of its 8-row span, 16B chunk
    // at element offset kelem (inverse of the read-side XOR).
    const int rowoff = lane >> 3;
    const int kelem  = ((lane & 7) ^ (lane >> 3)) << 3;
    const ushort* gA = Abase + (size_t)rowoff * lda + kelem;
    const ushort* gB = Bbase + (size_t)rowoff * ldb + kelem;
    const int raq0 = (wave < 4) ? (wave * 8) : (128 + (wave - 4) * 8); // A row base (+32*q)
    const int cb0  = wave * 8;                                         // B col base
    ushort* const ldsA0 = lds;           // A region (bytes [0,65536))
    ushort* const ldsB0 = lds + 32768;   // B region (bytes [65536,131072))
#define SAU(q_, st_, k0_) \
    async_cp16(gA + (size_t)(raq0 + 32 * (q_)) * lda + (k0_), \
               ldsA0 + (st_) * 16384 + (raq0 + 32 * (q_)) * 64)
#define SBH(h_, st_, k0_) do { \
    async_cp16(gB + (size_t)(cb0 + (h_) * 128) * ldb + (k0_), \
               ldsB0 + (st_) * 16384 + (h_) * 8192 + wave * 512); \
    async_cp16(gB + (size_t)(cb0 + (h_) * 128 + 64) * ldb + (k0_), \
               ldsB0 + (st_) * 16384 + (h_) * 8192 + 4096 + wave * 512); } while (0)
    // prologue: tile0 units in consumption order; keep [Au1,Au2,Au3] in flight
    SBH(0, 0, 0); SBH(1, 0, 0);
    SAU(0, 0, 0); SAU(1, 0, 0); SAU(2, 0, 0); SAU(3, 0, 0);
    asm volatile("s_waitcnt vmcnt(3)" ::: "memory");
    __builtin_amdgcn_s_barrier();
    bf16x8 a00, a01, a10, a11;
#define PHASE(q_, STAGES_, VMG_, VMNG_) do { \
    a00 = *(const bf16x8*)(sa + (2 * (q_)) * 2048 + kp0); \
    a01 = *(const bf16x8*)(sa + (2 * (q_)) * 2048 + kp1); \
    a10 = *(const bf16x8*)(sa + (2 * (q_) + 1) * 2048 + kp0); \
    a11 = *(const bf16x8*)(sa + (2 * (q_) + 1) * 2048 + kp1); \
    if (g) { STAGES_; } \
    asm volatile("s_waitcnt lgkmcnt(0)" ::: "memory"); \
    __builtin_amdgcn_sched_barrier(0); \
    __builtin_amdgcn_s_setprio(1); \
    _Pragma("unroll") \
    for (int j = 0; j < 4; ++j) { \
        acc[2 * (q_)][j]     = __builtin_amdgcn_mfma_f32_16x16x32_bf16(a00, b0[j], acc[2 * (q_)][j], 0, 0, 0); \
        acc[2 * (q_)][j]     = __builtin_amdgcn_mfma_f32_16x16x32_bf16(a01, b1[j], acc[2 * (q_)][j], 0, 0, 0); \
        acc[2 * (q_) + 1][j] = __builtin_amdgcn_mfma_f32_16x16x32_bf16(a10, b0[j], acc[2 * (q_) + 1][j], 0, 0, 0); \
        acc[2 * (q_) + 1][j] = __builtin_amdgcn_mfma_f32_16x16x32_bf16(a11, b1[j], acc[2 * (q_) + 1][j], 0, 0, 0); \
    } \
    __builtin_amdgcn_s_setprio(0); \
    if (g) { asm volatile("s_waitcnt vmcnt(" #VMG_ ")" ::: "memory"); } \
    else   { asm volatile("s_waitcnt vmcnt(" #VMNG_ ")" ::: "memory"); } \
    __builtin_amdgcn_s_barrier(); \
} while (0)
    for (int t = 0; t < nt; ++t) {
        const int sb = t & 1, st = sb ^ 1;
        const int k1 = (t + 1) << 6;
        const bool g = (t + 1 < nt);
        const char* sa  = ldsc + sb * 32768 + (wm * 128 + mr) * 128;
        const char* sbp = ldsc + 65536 + sb * 32768 + (wn * 64 + mr) * 128;
        bf16x8 b0[4], b1[4];
#pragma unroll
        for (int j = 0; j < 4; ++j) {
            b0[j] = *(const bf16x8*)(sbp + j * 2048 + kp0);
            b1[j] = *(const bf16x8*)(sbp + j * 2048 + kp1);
        }
        PHASE(0, SBH(0, st, k1), 4, 2);
        PHASE(1, SBH(1, st, k1), 5, 1);
        PHASE(2, SAU(0, st, k1); SAU(1, st, k1), 6, 0);
        PHASE(3, SAU(2, st, k1); SAU(3, st, k1), 3, 0);
    }
#undef PHASE
#undef SAU
#undef SBH
}

// gemm1: per-slot, XCD-grouped 1D grid so the 16 nt-siblings sharing an A panel
// land on one XCD's L2. F = (u%8) + 8*(nt + 16*(u/8)), u = slot*2 + mt.
__global__ __launch_bounds__(512, 2) void k_gemm1(
    const ushort* __restrict__ xb, const ushort* __restrict__ w1t,
    const float* __restrict__ b1, const int* __restrict__ slot_sample,
    ushort* __restrict__ H) {
    __shared__ __attribute__((aligned(16))) ushort lds[65536];   // 128 KiB
    unsigned F = blockIdx.x;
    int low3 = F & 7; unsigned rest = F >> 3;
    int nt_ = rest & 15; int g = rest >> 4;
    int u1 = g * 8 + low3;                 // 0..127
    int slot = u1 >> 1, mt = u1 & 1;
    int samp = slot_sample[slot];
    if (samp < 0) return;
    int e = slot >> 3;
    const ushort* Abase = xb + ((size_t)samp * S_ + mt * 256) * DIM_;
    const ushort* Bbase = w1t + (size_t)e * HID_ * DIM_ + (size_t)(nt_ * 256) * DIM_;
    f32x4 acc[8][4];
#pragma unroll
    for (int i = 0; i < 8; ++i)
#pragma unroll
        for (int j = 0; j < 4; ++j) acc[i][j] = (f32x4){0.f, 0.f, 0.f, 0.f};
    gemm_mainloop256(Abase, DIM_, Bbase, DIM_, DIM_, lds, acc);
    int wave = threadIdx.x >> 6, lane = threadIdx.x & 63;
    int wm = wave >> 2, wn = wave & 3, quad = lane >> 4, mr = lane & 15;
    ushort* Hrow = H + ((size_t)slot * S_ + mt * 256) * HID_ + nt_ * 256;
#pragma unroll
    for (int j = 0; j < 4; ++j) {
        int nl = wn * 64 + j * 16 + mr;
        float bias = b1[e * HID_ + nt_ * 256 + nl];
#pragma unroll
        for (int i = 0; i < 8; ++i) {
#pragma unroll
            for (int r = 0; r < 4; ++r) {
                int ml = wm * 128 + i * 16 + quad * 4 + r;
                float v = acc[i][j][r] + bias;
                float gl = 0.5f * v * (1.0f + erff(v * 0.70710678118654752f));
                Hrow[(size_t)ml * HID_ + nl] = f2bf(gl);
            }
        }
    }
}

// gemm2: per-sample (no atomics), XCD-grouped so the 4 nt-siblings sharing an
// H slab land on one XCD's L2. F = (u%8) + 8*(nt + 4*(u/8)), u = b*2 + mt.
__global__ __launch_bounds__(512, 2) void k_gemm2(
    const ushort* __restrict__ H, const ushort* __restrict__ w2t,
    const float* __restrict__ b2, const int* __restrict__ sample_slot,
    const float* __restrict__ sample_gate, float* __restrict__ out) {
    __shared__ __attribute__((aligned(16))) ushort lds[65536];   // 128 KiB
    unsigned F = blockIdx.x;
    int low3 = F & 7; unsigned rest = F >> 3;
    int nt_ = rest & 3; int g = rest >> 2;
    int u = g * 8 + low3;                  // 0..63
    int b = u >> 1, mt = u & 1;
    int sl0 = sample_slot[b * TOPK_ + 0], sl1 = sample_slot[b * TOPK_ + 1];
    float ga0 = sample_gate[b * TOPK_ + 0], ga1 = sample_gate[b * TOPK_ + 1];
    if (sl0 < 0) { sl0 = sl1; ga0 = ga1; sl1 = -1; }
    f32x4 acc[8][4];
#pragma unroll
    for (int i = 0; i < 8; ++i)
#pragma unroll
        for (int j = 0; j < 4; ++j) acc[i][j] = (f32x4){0.f, 0.f, 0.f, 0.f};
    if (sl0 >= 0) {
        int e0 = sl0 >> 3;
        gemm_mainloop256(H + ((size_t)sl0 * S_ + mt * 256) * HID_, HID_,
                         w2t + (size_t)e0 * DIM_ * HID_ + (size_t)(nt_ * 256) * HID_, HID_,
                         HID_, lds, acc);
    }
    if (sl1 >= 0) {
        float ratio = ga0 / ga1;
#pragma unroll
        for (int i = 0; i < 8; ++i)
#pragma unroll
            for (int j = 0; j < 4; ++j) acc[i][j] = acc[i][j] * ratio;
        int e1 = sl1 >> 3;
        gemm_mainloop256(H + ((size_t)sl1 * S_ + mt * 256) * HID_, HID_,
                         w2t + (size_t)e1 * DIM_ * HID_ + (size_t)(nt_ * 256) * HID_, HID_,
                         HID_, lds, acc);
    }
    float gfin = (sl1 >= 0) ? ga1 : ((sl0 >= 0) ? ga0 : 0.f);
    int wave = threadIdx.x >> 6, lane = threadIdx.x & 63;
    int wm = wave >> 2, wn = wave & 3, quad = lane >> 4, mr = lane & 15;
    float* Orow = out + ((size_t)b * S_ + mt * 256) * DIM_ + nt_ * 256;
#pragma unroll
    for (int j = 0; j < 4; ++j) {
        int nl = wn * 64 + j * 16 + mr;
        float bias = 0.f;
        if (sl0 >= 0) bias += ga0 * b2[(sl0 >> 3) * DIM_ + nt_ * 256 + nl];
        if (sl1 >= 0) bias += ga1 * b2[(sl1 >> 3) * DIM_ + nt_ * 256 + nl];
#pragma unroll
        for (int i = 0; i < 8; ++i) {
#pragma unroll
            for (int r = 0; r < 4; ++r) {
                int ml = wm * 128 + i * 16 + quad * 4 + r;
                Orow[(size_t)ml * DIM_ + nl] = acc[i][j][r] * gfin + bias;
            }
        }
    }
}

// ---------------- launch ----------------
extern "C" void kernel_launch(void* const* d_in, const int* in_sizes, int n_in,
                              void* d_out, int out_size, void* d_ws, size_t ws_size,
                              hipStream_t stream) {
    const float* rin   = (const float*)d_in[0];
    const float* x     = (const float*)d_in[1];
    const float* noise = (const float*)d_in[2];
    const float* Wg    = (const float*)d_in[3];
    const float* bg    = (const float*)d_in[4];
    const float* Wn    = (const float*)d_in[5];
    const float* bn    = (const float*)d_in[6];
    const float* W1    = (const float*)d_in[7];
    const float* b1    = (const float*)d_in[8];
    const float* W2    = (const float*)d_in[9];
    const float* b2    = (const float*)d_in[10];
    float* out = (float*)d_out;

    char* ws = (char*)d_ws;
    float*  ri          = (float*)ws;
    int*    slot_sample = (int*)(ws + 131072);
    float*  slot_gate   = (float*)(ws + 131328);
    int*    sample_slot = (int*)(ws + 131584);
    float*  sample_gate = (float*)(ws + 131840);
    ushort* xb  = (ushort*)(ws + 135168);                           // 32 MB
    ushort* w1t = (ushort*)(ws + 135168 + 33554432);                // 64 MB
    ushort* w2t = (ushort*)(ws + 135168 + 33554432 + 67108864);     // 64 MB
    ushort* H   = (ushort*)(ws + 135168 + 33554432 + 2 * 67108864); // 256 MB
    float* part  = (float*)H;                                       // scratch (pre-gemm1)
    float* noisy = (float*)((char*)H + 2097152);

    k_mean_p<<<dim3(16, B_), 256, 0, stream>>>(rin, part);
    k_mean_f<<<B_, 256, 0, stream>>>(part, ri);
    k_router_logits<<<B_, 256, 0, stream>>>(ri, noise, Wg, bg, Wn, bn, noisy);
    k_router_assign<<<1, 256, 0, stream>>>(noisy, slot_sample, slot_gate,
                                           sample_slot, sample_gate);
    k_cvt_x<<<(B_ * S_ * DIM_ / 8 + 255) / 256, 256, 0, stream>>>(x, xb, B_ * S_ * DIM_ / 8);
    k_transpose_cvt<<<dim3(HID_ / 64, DIM_ / 64, E_), 256, 0, stream>>>(W1, w1t, DIM_, HID_);
    k_transpose_cvt<<<dim3(DIM_ / 64, HID_ / 64, E_), 256, 0, stream>>>(W2, w2t, HID_, DIM_);
    k_gemm1<<<128 * 16, 512, 0, stream>>>(xb, w1t, b1, slot_sample, H);
    k_gemm2<<<64 * 4, 512, 0, stream>>>(H, w2t, b2, sample_slot, sample_gate, out);
}